// Round 3
// baseline (2561.336 us; speedup 1.0000x reference)
//
#include <hip/hip_runtime.h>
#include <hip/hip_bf16.h>

typedef unsigned short u16;
typedef __attribute__((ext_vector_type(8))) short short8;
typedef __attribute__((ext_vector_type(4))) float floatx4;

__device__ __forceinline__ u16 f2bf(float x) {
  unsigned u = __float_as_uint(x);
  u += 0x7fffu + ((u >> 16) & 1u);           // round-to-nearest-even to bf16
  return (u16)(u >> 16);
}
__device__ __forceinline__ float bf2f(u16 u) {
  return __uint_as_float(((unsigned)u) << 16);
}
__device__ __forceinline__ float sigm(float x) {
  return 1.0f / (1.0f + __expf(-x));
}

// ---------------- prep kernels ----------------

// x1,x2: (B=4, T=8, 128, 32, 32) fp32 -> X: [t][b][1024 pix][256 ch] bf16 hi/lo
// Thread index == input index (coalesced reads; scattered u16 stores absorbed by L2).
__global__ __launch_bounds__(256) void xsplit_kernel(
    const float* __restrict__ x1, const float* __restrict__ x2,
    u16* __restrict__ Xh, u16* __restrict__ Xl)
{
  int i = blockIdx.x * 256 + threadIdx.x;   // 2^23 total
  int sel = i >> 22;                        // 0: x1, 1: x2
  int j = i & 4194303;
  int pix = j & 1023;
  int c   = (j >> 10) & 127;
  int t   = (j >> 17) & 7;
  int b   = j >> 20;
  const float* src = sel ? x2 : x1;
  float v = src[j];                         // layout matches j decomposition
  int c2 = c + (sel << 7);
  size_t o = ((size_t)((t * 4 + b) * 1024 + pix) << 8) + c2;
  u16 h = f2bf(v);
  Xh[o] = h;
  Xl[o] = f2bf(v - bf2f(h));
}

// W: (512, CIN, 3, 3) fp32 -> Wr: [n=512][k = (ky*3+kx)*CIN + ci] bf16 hi/lo
__global__ __launch_bounds__(256) void wsplit_kernel(
    const float* __restrict__ W, u16* __restrict__ Wh, u16* __restrict__ Wl, int CIN)
{
  int K = CIN * 9;
  int i = blockIdx.x * 256 + threadIdx.x;   // grid sized exactly 512*K/256
  int n = i / K;
  int k = i - n * K;
  int e9 = k / CIN;
  int ci = k - e9 * CIN;
  float v = W[((size_t)n * CIN + ci) * 9 + e9];
  u16 h = f2bf(v);
  Wh[i] = h;
  Wl[i] = f2bf(v - bf2f(h));
}

__global__ __launch_bounds__(256) void init_state(
    float* __restrict__ c1, float* __restrict__ c2, float* __restrict__ c3,
    u16* __restrict__ h1h, u16* __restrict__ h1l,
    u16* __restrict__ h2h, u16* __restrict__ h2l,
    u16* __restrict__ h3h, u16* __restrict__ h3l)
{
  int i = blockIdx.x * 256 + threadIdx.x;   // 524288
  c1[i] = 0.f; c2[i] = 0.f; c3[i] = 0.f;
  h1h[i] = 0; h1l[i] = 0; h2h[i] = 0; h2l[i] = 0; h3h[i] = 0; h3l[i] = 0;
}

// ---------------- conv as GEMM (pixel-major activations, split-K over ky) ----
// z[n][m] = sum_k A[m][k]*W[n][k]; m=(b,pix); k=(ky,kx,ci).
// Activations pixel-major: A1 = [b][1024][CA], A2 = [b][1024][CB] bf16 hi/lo.
// blockIdx.y = kg = ky (0..2); block covers 64 m x 64 n, K' = 3*CIN.
// hi/lo split: acc += Ah*Wh + Ah*Wl + Al*Wh.
__global__ __launch_bounds__(256) void conv_gemm(
    const u16* __restrict__ A1h, const u16* __restrict__ A1l, int CA,
    const u16* __restrict__ A2h, const u16* __restrict__ A2l, int CB,
    const u16* __restrict__ Wh, const u16* __restrict__ Wl,
    float* __restrict__ zpart)
{
  const int CIN = CA + CB;
  const int K = CIN * 9;
  const int kg = blockIdx.y;                 // ky; dy = kg-1

  __shared__ __align__(16) char smem[24576];
  u16 (*Ah)[48] = reinterpret_cast<u16(*)[48]>(smem);           // 64 x 48, 96B stride (16B-aligned)
  u16 (*Al)[48] = reinterpret_cast<u16(*)[48]>(smem + 6144);
  u16 (*Bh)[48] = reinterpret_cast<u16(*)[48]>(smem + 12288);   // [n][k]
  u16 (*Bl)[48] = reinterpret_cast<u16(*)[48]>(smem + 18432);

  int tid = threadIdx.x;
  int bx  = blockIdx.x;
  int nt = bx & 7;          // 8 n-tiles
  int mt = bx >> 3;         // 64 m-tiles
  int m0 = mt * 64;
  int b  = m0 >> 10;
  int pbase = m0 & 1023;    // pixel offset within batch (multiple of 64)

  // A staging roles: p = tile pixel, cq = 8-ch chunk
  int p  = tid >> 2;        // 0..63
  int cq = (tid & 3) * 8;
  int gy = (pbase >> 5) + (p >> 5);
  int gx = p & 31;
  int dy = kg - 1;
  int yy = gy + dy;
  bool vy = ((unsigned)yy < 32u);

  // B staging roles
  int bn = tid >> 2;        // n row 0..63
  int bk = (tid & 3) * 8;
  const size_t wrow = (size_t)(nt * 64 + bn) * K + bk;

  int lane = tid & 63;
  int wid  = tid >> 6;
  int wm = wid >> 1, wn = wid & 1;
  int fr = lane & 15, kq = lane >> 4;

  floatx4 acc[2][2];
  #pragma unroll
  for (int i2 = 0; i2 < 2; ++i2)
    #pragma unroll
    for (int j2 = 0; j2 < 2; ++j2)
      acc[i2][j2] = (floatx4)0.0f;

  for (int j = 0; j < 3; ++j) {
    int dx = j - 1;
    int xx = gx + dx;
    bool valid = vy & ((unsigned)xx < 32u);
    int sp = yy * 32 + xx;                  // used only when valid
    int e9 = kg * 3 + j;
    for (int cc = 0; cc < CIN; cc += 32) {
      // ---- issue loads early (before barrier) ----
      const u16 *sh, *sl; int coff, CH;
      if (cc < CA) { sh = A1h; sl = A1l; coff = cc;      CH = CA; }
      else         { sh = A2h; sl = A2l; coff = cc - CA; CH = CB; }
      short8 vh = (short8)0, vl = (short8)0;
      if (valid) {
        size_t ab = ((size_t)(b * 1024 + sp)) * CH + coff + cq;
        vh = *reinterpret_cast<const short8*>(sh + ab);
        vl = *reinterpret_cast<const short8*>(sl + ab);
      }
      size_t wb = wrow + (size_t)e9 * CIN + cc;
      short8 wvh = *reinterpret_cast<const short8*>(Wh + wb);
      short8 wvl = *reinterpret_cast<const short8*>(Wl + wb);

      __syncthreads();   // previous chunk's frag reads complete
      *reinterpret_cast<short8*>(&Ah[p][cq]) = vh;
      *reinterpret_cast<short8*>(&Al[p][cq]) = vl;
      *reinterpret_cast<short8*>(&Bh[bn][bk]) = wvh;
      *reinterpret_cast<short8*>(&Bl[bn][bk]) = wvl;
      __syncthreads();

      // ---- fragments + 12 MFMA ----
      short8 va_h[2], va_l[2], vb_h[2], vb_l[2];
      #pragma unroll
      for (int f = 0; f < 2; ++f) {
        va_h[f] = *reinterpret_cast<const short8*>(&Ah[wm * 32 + f * 16 + fr][kq * 8]);
        va_l[f] = *reinterpret_cast<const short8*>(&Al[wm * 32 + f * 16 + fr][kq * 8]);
        vb_h[f] = *reinterpret_cast<const short8*>(&Bh[wn * 32 + f * 16 + fr][kq * 8]);
        vb_l[f] = *reinterpret_cast<const short8*>(&Bl[wn * 32 + f * 16 + fr][kq * 8]);
      }
      #pragma unroll
      for (int mf = 0; mf < 2; ++mf)
        #pragma unroll
        for (int nf = 0; nf < 2; ++nf) {
          acc[mf][nf] = __builtin_amdgcn_mfma_f32_16x16x32_bf16(va_h[mf], vb_h[nf], acc[mf][nf], 0, 0, 0);
          acc[mf][nf] = __builtin_amdgcn_mfma_f32_16x16x32_bf16(va_h[mf], vb_l[nf], acc[mf][nf], 0, 0, 0);
          acc[mf][nf] = __builtin_amdgcn_mfma_f32_16x16x32_bf16(va_l[mf], vb_h[nf], acc[mf][nf], 0, 0, 0);
        }
    }
  }

  __syncthreads();   // all frag reads done before smem reuse

  // ---- epilogue: per-wave 32x32 transpose (stride 33 to dodge conflicts) ----
  float* tr = reinterpret_cast<float*>(smem) + wid * 1089;   // 33*33 region/wave
  #pragma unroll
  for (int mf = 0; mf < 2; ++mf)
    #pragma unroll
    for (int nf = 0; nf < 2; ++nf)
      #pragma unroll
      for (int r = 0; r < 4; ++r)
        tr[(nf * 16 + fr) * 33 + mf * 16 + kq * 4 + r] = acc[mf][nf][r];
  __syncthreads();
  float* zp = zpart + (size_t)kg * 2097152;
  int n_base = nt * 64 + wn * 32;
  int m_base = m0 + wm * 32;
  #pragma unroll
  for (int it = 0; it < 4; ++it) {
    int row = it * 8 + (lane >> 3);
    int mq  = (lane & 7) * 4;
    floatx4 v;
    #pragma unroll
    for (int r = 0; r < 4; ++r) v[r] = tr[row * 33 + mq + r];
    *reinterpret_cast<floatx4*>(&zp[(size_t)(n_base + row) * 4096 + m_base + mq]) = v;
  }
}

// ---------------- fused gates + state update ----------------
// z partials: 3 x [512][4096]. c,h pixel-major: [b][1024][128]. h stored bf16 hi/lo.
__global__ __launch_bounds__(256) void gate_kernel(
    const float* __restrict__ z, const float* __restrict__ bias,
    float* __restrict__ c, u16* __restrict__ hh, u16* __restrict__ hl,
    float* __restrict__ hout)
{
  int g = blockIdx.x * 256 + threadIdx.x;   // (b, pix, oc) — oc fastest
  int oc  = g & 127;
  int pix = (g >> 7) & 1023;
  int b   = g >> 17;
  size_t m = ((size_t)b << 10) + pix;
  float zv[4];
  #pragma unroll
  for (int G = 0; G < 4; ++G) {
    size_t r = (size_t)(G * 128 + oc) * 4096 + m;
    zv[G] = z[r] + z[2097152 + r] + z[4194304 + r] + bias[G * 128 + oc];
  }
  float cv = c[g];
  float cn = sigm(zv[1]) * cv + sigm(zv[0]) * tanhf(zv[3]);
  float hn = sigm(zv[2]) * tanhf(cn);
  c[g] = cn;
  u16 hb = f2bf(hn);
  hh[g] = hb;
  hl[g] = f2bf(hn - bf2f(hb));
  if (hout) hout[((size_t)(b * 128 + oc) << 10) + pix] = hn;  // NCHW output
}

extern "C" void kernel_launch(void* const* d_in, const int* in_sizes, int n_in,
                              void* d_out, int out_size, void* d_ws, size_t ws_size,
                              hipStream_t stream)
{
  const float* x1 = (const float*)d_in[0];
  const float* x2 = (const float*)d_in[1];
  const float* W1 = (const float*)d_in[2];
  const float* b1 = (const float*)d_in[3];
  const float* W2 = (const float*)d_in[4];
  const float* b2 = (const float*)d_in[5];
  const float* W3 = (const float*)d_in[6];
  const float* b3 = (const float*)d_in[7];
  float* out = (float*)d_out;

  char* ws = (char*)d_ws;
  size_t off = 0;
  auto alloc = [&](size_t bytes) {
    char* p = ws + off;
    off += (bytes + 255) & ~(size_t)255;
    return p;
  };
  u16*   Xh  = (u16*)  alloc(16777216);   // [8][4][1024][256] bf16
  u16*   Xl  = (u16*)  alloc(16777216);
  u16*   W1h = (u16*)  alloc(3538944);    // [512][3456]
  u16*   W1l = (u16*)  alloc(3538944);
  u16*   W2h = (u16*)  alloc(2359296);    // [512][2304]
  u16*   W2l = (u16*)  alloc(2359296);
  u16*   W3h = (u16*)  alloc(2359296);
  u16*   W3l = (u16*)  alloc(2359296);
  u16*   h1h = (u16*)  alloc(1048576);    // [4][1024][128] bf16
  u16*   h1l = (u16*)  alloc(1048576);
  u16*   h2h = (u16*)  alloc(1048576);
  u16*   h2l = (u16*)  alloc(1048576);
  u16*   h3h = (u16*)  alloc(1048576);
  u16*   h3l = (u16*)  alloc(1048576);
  float* c1  = (float*)alloc(2097152);    // [4][1024][128] fp32
  float* c2  = (float*)alloc(2097152);
  float* c3  = (float*)alloc(2097152);
  float* z   = (float*)alloc(25165824);   // 3 x [512][4096] fp32 partials
  if (off > ws_size) return;              // clean fail if workspace too small

  xsplit_kernel<<<32768, 256, 0, stream>>>(x1, x2, Xh, Xl);
  wsplit_kernel<<<6912, 256, 0, stream>>>(W1, W1h, W1l, 384);
  wsplit_kernel<<<4608, 256, 0, stream>>>(W2, W2h, W2l, 256);
  wsplit_kernel<<<4608, 256, 0, stream>>>(W3, W3h, W3l, 256);
  init_state<<<2048, 256, 0, stream>>>(c1, c2, c3, h1h, h1l, h2h, h2l, h3h, h3l);

  dim3 cgrid(512, 3);
  for (int t = 0; t < 8; ++t) {
    const u16* Xth = Xh + (size_t)t * 1048576;
    const u16* Xtl = Xl + (size_t)t * 1048576;
    // layer 1: [x_t (256ch), h1 (128ch)] -> gates -> h1,c1
    conv_gemm<<<cgrid, 256, 0, stream>>>(Xth, Xtl, 256, h1h, h1l, 128, W1h, W1l, z);
    gate_kernel<<<2048, 256, 0, stream>>>(z, b1, c1, h1h, h1l, nullptr);
    // layer 2: [h1, h2]
    conv_gemm<<<cgrid, 256, 0, stream>>>(h1h, h1l, 128, h2h, h2l, 128, W2h, W2l, z);
    gate_kernel<<<2048, 256, 0, stream>>>(z, b2, c2, h2h, h2l, nullptr);
    // layer 3: [h2, h3]
    conv_gemm<<<cgrid, 256, 0, stream>>>(h2h, h2l, 128, h3h, h3l, 128, W3h, W3l, z);
    gate_kernel<<<2048, 256, 0, stream>>>(z, b3, c3, h3h, h3l, (t == 7) ? out : nullptr);
  }
}

// Round 4
// 1643.342 us; speedup vs baseline: 1.5586x; 1.5586x over previous
//
#include <hip/hip_runtime.h>
#include <hip/hip_bf16.h>

typedef unsigned short u16;
typedef __attribute__((ext_vector_type(8))) short short8;
typedef __attribute__((ext_vector_type(4))) float floatx4;

__device__ __forceinline__ u16 f2bf(float x) {
  unsigned u = __float_as_uint(x);
  u += 0x7fffu + ((u >> 16) & 1u);           // round-to-nearest-even to bf16
  return (u16)(u >> 16);
}
__device__ __forceinline__ float bf2f(u16 u) {
  return __uint_as_float(((unsigned)u) << 16);
}
__device__ __forceinline__ float sigm(float x) {
  return 1.0f / (1.0f + __expf(-x));
}

// ---------------- prep kernels ----------------

// x1,x2: (B=4, T=8, 128, 32, 32) fp32 -> X: [slot=t*4+b][1024 pix][256 ch] bf16 hi/lo
// LDS-transpose: coalesced float4 reads, coalesced short8 writes.
__global__ __launch_bounds__(256) void xsplit_kernel(
    const float* __restrict__ x1, const float* __restrict__ x2,
    u16* __restrict__ Xh, u16* __restrict__ Xl)
{
  __shared__ float lds[128][65];     // +1 pad: transpose reads conflict-light
  int bx  = blockIdx.x;              // 1024 blocks
  int sel = bx >> 9;                 // 0: x1, 1: x2
  int rem = bx & 511;
  int bt  = rem >> 4;                // b*8+t (source layout order)
  int pg  = rem & 15;                // 64-pixel group
  int b = bt >> 3, t = bt & 7;
  int p0 = pg << 6;
  const float* src = (sel ? x2 : x1) + ((size_t)bt << 17);   // + (b*8+t)*128*1024
  int tid = threadIdx.x;
  #pragma unroll
  for (int k2 = 0; k2 < 8; ++k2) {   // 128 ch x 16 float4 = 2048 quads
    int idx = tid + (k2 << 8);
    int c = idx >> 4, p4 = (idx & 15) << 2;
    floatx4 v = *reinterpret_cast<const floatx4*>(src + ((size_t)c << 10) + p0 + p4);
    lds[c][p4] = v[0]; lds[c][p4 + 1] = v[1]; lds[c][p4 + 2] = v[2]; lds[c][p4 + 3] = v[3];
  }
  __syncthreads();
  int pl = tid >> 2;                 // pixel 0..63
  int cg = (tid & 3) << 5;           // channel group 0/32/64/96
  size_t obase = (((size_t)((t * 4 + b) * 1024 + p0 + pl)) << 8) + (sel << 7) + cg;
  #pragma unroll
  for (int q = 0; q < 4; ++q) {
    short8 hv, lv;
    #pragma unroll
    for (int j = 0; j < 8; ++j) {
      float f = lds[cg + q * 8 + j][pl];
      u16 h = f2bf(f);
      hv[j] = (short)h;
      lv[j] = (short)f2bf(f - bf2f(h));
    }
    *reinterpret_cast<short8*>(Xh + obase + q * 8) = hv;
    *reinterpret_cast<short8*>(Xl + obase + q * 8) = lv;
  }
}

// W: (512, CIN, 3, 3) fp32 -> Wr: [n=512][k = (ky*3+kx)*CIN + ci] bf16 hi/lo
__global__ __launch_bounds__(256) void wsplit_kernel(
    const float* __restrict__ W, u16* __restrict__ Wh, u16* __restrict__ Wl, int CIN)
{
  int K = CIN * 9;
  int i = blockIdx.x * 256 + threadIdx.x;   // grid sized exactly 512*K/256
  int n = i / K;
  int k = i - n * K;
  int e9 = k / CIN;
  int ci = k - e9 * CIN;
  float v = W[((size_t)n * CIN + ci) * 9 + e9];
  u16 h = f2bf(v);
  Wh[i] = h;
  Wl[i] = f2bf(v - bf2f(h));
}

__global__ __launch_bounds__(256) void init_state(
    float* __restrict__ c1, float* __restrict__ c2, float* __restrict__ c3,
    u16* __restrict__ h1h, u16* __restrict__ h1l,
    u16* __restrict__ h2h, u16* __restrict__ h2l,
    u16* __restrict__ h3h, u16* __restrict__ h3l)
{
  int i = blockIdx.x * 256 + threadIdx.x;   // 524288
  c1[i] = 0.f; c2[i] = 0.f; c3[i] = 0.f;
  h1h[i] = 0; h1l[i] = 0; h2h[i] = 0; h2l[i] = 0; h3h[i] = 0; h3l[i] = 0;
}

// ---------------- conv as GEMM (pixel-major activations) ----------------
// z[m][n] (+N=512) = sum_k A[m][k]*W[n][k]; m=(slot,pix); k=(ky,kx,ci).
// A1 = [slot][1024][CA], A2 = [slot][1024][CB] bf16 hi/lo (A2 optional, CB=0).
// Weights: Wr[n][e9*WCIN + wcoff + ci] (wcoff selects a channel sub-range).
// kg (=ky) handling: seq convs use gridDim.y=3, kgpb=1 (split-K partials,
// zp = zpart + blockIdx.y*zstride); big GEMM uses gridDim.y=1, kgpb=3 (full sum).
// hi/lo split: acc += Ah*Wh + Ah*Wl + Al*Wh.
__global__ __launch_bounds__(256) void conv_gemm(
    const u16* __restrict__ A1h, const u16* __restrict__ A1l, int CA,
    const u16* __restrict__ A2h, const u16* __restrict__ A2l, int CB,
    const u16* __restrict__ Wh, const u16* __restrict__ Wl,
    int WCIN, int wcoff, int WK,
    float* __restrict__ zpart, int zstride, int kgpb)
{
  const int CIN = CA + CB;

  __shared__ __align__(16) char smem[24576];
  u16 (*Ah)[48] = reinterpret_cast<u16(*)[48]>(smem);           // 64 x 48, 96B stride
  u16 (*Al)[48] = reinterpret_cast<u16(*)[48]>(smem + 6144);
  u16 (*Bh)[48] = reinterpret_cast<u16(*)[48]>(smem + 12288);   // [n][k]
  u16 (*Bl)[48] = reinterpret_cast<u16(*)[48]>(smem + 18432);

  int tid = threadIdx.x;
  int bx  = blockIdx.x;
  int nt = bx & 7;          // 8 n-tiles
  int mt = bx >> 3;         // m-tiles
  int m0 = mt * 64;
  int slot = m0 >> 10;      // batch slot (b or t*4+b)
  int pbase = m0 & 1023;

  // A staging roles: p = tile pixel, cq = 8-ch chunk
  int p  = tid >> 2;        // 0..63
  int cq = (tid & 3) * 8;
  int gy = (pbase >> 5) + (p >> 5);
  int gx = p & 31;

  // B staging roles
  int bn = tid >> 2;        // n row 0..63
  int bk = (tid & 3) * 8;
  const size_t wrow = (size_t)(nt * 64 + bn) * WK + wcoff + bk;

  int lane = tid & 63;
  int wid  = tid >> 6;
  int wm = wid >> 1, wn = wid & 1;
  int fr = lane & 15, kq = lane >> 4;

  floatx4 acc[2][2];
  #pragma unroll
  for (int i2 = 0; i2 < 2; ++i2)
    #pragma unroll
    for (int j2 = 0; j2 < 2; ++j2)
      acc[i2][j2] = (floatx4)0.0f;

  for (int kgi = 0; kgi < kgpb; ++kgi) {
    int kg = blockIdx.y * kgpb + kgi;
    int yy = gy + kg - 1;
    bool vy = ((unsigned)yy < 32u);
    for (int j = 0; j < 3; ++j) {
      int xx = gx + j - 1;
      bool valid = vy & ((unsigned)xx < 32u);
      int sp = yy * 32 + xx;                  // used only when valid
      int e9 = kg * 3 + j;
      for (int cc = 0; cc < CIN; cc += 32) {
        // ---- issue loads early (before barrier) ----
        const u16 *sh, *sl; int coff, CH;
        if (cc < CA) { sh = A1h; sl = A1l; coff = cc;      CH = CA; }
        else         { sh = A2h; sl = A2l; coff = cc - CA; CH = CB; }
        short8 vh = (short8)0, vl = (short8)0;
        if (valid) {
          size_t ab = ((size_t)(slot * 1024 + sp)) * CH + coff + cq;
          vh = *reinterpret_cast<const short8*>(sh + ab);
          vl = *reinterpret_cast<const short8*>(sl + ab);
        }
        size_t wb = wrow + (size_t)e9 * WCIN + cc;
        short8 wvh = *reinterpret_cast<const short8*>(Wh + wb);
        short8 wvl = *reinterpret_cast<const short8*>(Wl + wb);

        __syncthreads();   // previous chunk's frag reads complete
        *reinterpret_cast<short8*>(&Ah[p][cq]) = vh;
        *reinterpret_cast<short8*>(&Al[p][cq]) = vl;
        *reinterpret_cast<short8*>(&Bh[bn][bk]) = wvh;
        *reinterpret_cast<short8*>(&Bl[bn][bk]) = wvl;
        __syncthreads();

        // ---- fragments + 12 MFMA ----
        short8 va_h[2], va_l[2], vb_h[2], vb_l[2];
        #pragma unroll
        for (int f = 0; f < 2; ++f) {
          va_h[f] = *reinterpret_cast<const short8*>(&Ah[wm * 32 + f * 16 + fr][kq * 8]);
          va_l[f] = *reinterpret_cast<const short8*>(&Al[wm * 32 + f * 16 + fr][kq * 8]);
          vb_h[f] = *reinterpret_cast<const short8*>(&Bh[wn * 32 + f * 16 + fr][kq * 8]);
          vb_l[f] = *reinterpret_cast<const short8*>(&Bl[wn * 32 + f * 16 + fr][kq * 8]);
        }
        #pragma unroll
        for (int mf = 0; mf < 2; ++mf)
          #pragma unroll
          for (int nf = 0; nf < 2; ++nf) {
            acc[mf][nf] = __builtin_amdgcn_mfma_f32_16x16x32_bf16(va_h[mf], vb_h[nf], acc[mf][nf], 0, 0, 0);
            acc[mf][nf] = __builtin_amdgcn_mfma_f32_16x16x32_bf16(va_h[mf], vb_l[nf], acc[mf][nf], 0, 0, 0);
            acc[mf][nf] = __builtin_amdgcn_mfma_f32_16x16x32_bf16(va_l[mf], vb_h[nf], acc[mf][nf], 0, 0, 0);
          }
      }
    }
  }

  // ---- epilogue: direct z[m][n] stores (16-lane / 64B coalesced groups) ----
  float* zp = zpart + (size_t)blockIdx.y * zstride;
  #pragma unroll
  for (int mf = 0; mf < 2; ++mf)
    #pragma unroll
    for (int nf = 0; nf < 2; ++nf) {
      int n = nt * 64 + wn * 32 + nf * 16 + fr;
      int mbase = m0 + wm * 32 + mf * 16 + kq * 4;
      #pragma unroll
      for (int r = 0; r < 4; ++r)
        zp[((size_t)(mbase + r) << 9) + n] = acc[mf][nf][r];
    }
}

// ---------------- fused gates + state update ----------------
// z: 3 partials of [4096 m][512 n] (zstride 2097152); zx: optional extra term
// (same [m][n] indexing). c,h pixel-major: [b][1024][128]; h stored bf16 hi/lo.
__global__ __launch_bounds__(256) void gate_kernel(
    const float* __restrict__ z, const float* __restrict__ zx,
    const float* __restrict__ bias,
    float* __restrict__ c, u16* __restrict__ hh, u16* __restrict__ hl,
    float* __restrict__ hout)
{
  int g = blockIdx.x * 256 + threadIdx.x;   // (b, pix, oc) — oc fastest
  int oc  = g & 127;
  int pix = (g >> 7) & 1023;
  int b   = g >> 17;
  size_t mrow = ((size_t)(b * 1024 + pix)) << 9;
  float zv[4];
  #pragma unroll
  for (int G = 0; G < 4; ++G) {
    size_t r = mrow + G * 128 + oc;
    float s = z[r] + z[2097152 + r] + z[4194304 + r] + bias[G * 128 + oc];
    if (zx) s += zx[r];
    zv[G] = s;
  }
  float cv = c[g];
  float cn = sigm(zv[1]) * cv + sigm(zv[0]) * tanhf(zv[3]);
  float hn = sigm(zv[2]) * tanhf(cn);
  c[g] = cn;
  u16 hb = f2bf(hn);
  hh[g] = hb;
  hl[g] = f2bf(hn - bf2f(hb));
  if (hout) hout[((size_t)(b * 128 + oc) << 10) + pix] = hn;  // NCHW output
}

extern "C" void kernel_launch(void* const* d_in, const int* in_sizes, int n_in,
                              void* d_out, int out_size, void* d_ws, size_t ws_size,
                              hipStream_t stream)
{
  const float* x1 = (const float*)d_in[0];
  const float* x2 = (const float*)d_in[1];
  const float* W1 = (const float*)d_in[2];
  const float* b1 = (const float*)d_in[3];
  const float* W2 = (const float*)d_in[4];
  const float* b2 = (const float*)d_in[5];
  const float* W3 = (const float*)d_in[6];
  const float* b3 = (const float*)d_in[7];
  float* out = (float*)d_out;

  char* ws = (char*)d_ws;
  size_t off = 0;
  auto alloc = [&](size_t bytes) {
    char* p = ws + off;
    off += (bytes + 255) & ~(size_t)255;
    return p;
  };
  u16*   Xh  = (u16*)  alloc(16777216);   // [32 slot][1024][256] bf16
  u16*   Xl  = (u16*)  alloc(16777216);
  u16*   W1h = (u16*)  alloc(3538944);    // [512][3456]
  u16*   W1l = (u16*)  alloc(3538944);
  u16*   W2h = (u16*)  alloc(2359296);    // [512][2304]
  u16*   W2l = (u16*)  alloc(2359296);
  u16*   W3h = (u16*)  alloc(2359296);
  u16*   W3l = (u16*)  alloc(2359296);
  u16*   h1h = (u16*)  alloc(1048576);    // [4][1024][128] bf16
  u16*   h1l = (u16*)  alloc(1048576);
  u16*   h2h = (u16*)  alloc(1048576);
  u16*   h2l = (u16*)  alloc(1048576);
  u16*   h3h = (u16*)  alloc(1048576);
  u16*   h3l = (u16*)  alloc(1048576);
  float* c1  = (float*)alloc(2097152);    // [4][1024][128] fp32
  float* c2  = (float*)alloc(2097152);
  float* c3  = (float*)alloc(2097152);
  float* zx  = (float*)alloc(67108864);   // [32 slot][1024][512] fp32: L1 x-part, all T
  float* z   = (float*)alloc(25165824);   // 3 x [4096][512] fp32 partials
  if (off > ws_size) return;              // clean fail if workspace too small

  xsplit_kernel<<<1024, 256, 0, stream>>>(x1, x2, Xh, Xl);
  wsplit_kernel<<<6912, 256, 0, stream>>>(W1, W1h, W1l, 384);
  wsplit_kernel<<<4608, 256, 0, stream>>>(W2, W2h, W2l, 256);
  wsplit_kernel<<<4608, 256, 0, stream>>>(W3, W3h, W3l, 256);
  init_state<<<2048, 256, 0, stream>>>(c1, c2, c3, h1h, h1l, h2h, h2l, h3h, h3l);

  // big GEMM: L1 x-contribution for all T (M=32768, K=2304), full K per block
  conv_gemm<<<dim3(4096, 1), 256, 0, stream>>>(
      Xh, Xl, 256, nullptr, nullptr, 0, W1h, W1l, 384, 0, 3456, zx, 0, 3);

  dim3 cgrid(512, 3);
  for (int t = 0; t < 8; ++t) {
    const float* zxt = zx + (size_t)t * 2097152;
    // layer 1 (h-part only, K=1152): weights channels 256..383 of W1
    conv_gemm<<<cgrid, 256, 0, stream>>>(
        h1h, h1l, 128, nullptr, nullptr, 0, W1h, W1l, 384, 256, 3456, z, 2097152, 1);
    gate_kernel<<<2048, 256, 0, stream>>>(z, zxt, b1, c1, h1h, h1l, nullptr);
    // layer 2: [h1, h2]
    conv_gemm<<<cgrid, 256, 0, stream>>>(
        h1h, h1l, 128, h2h, h2l, 128, W2h, W2l, 256, 0, 2304, z, 2097152, 1);
    gate_kernel<<<2048, 256, 0, stream>>>(z, nullptr, b2, c2, h2h, h2l, nullptr);
    // layer 3: [h2, h3]
    conv_gemm<<<cgrid, 256, 0, stream>>>(
        h2h, h2l, 128, h3h, h3l, 128, W3h, W3l, 256, 0, 2304, z, 2097152, 1);
    gate_kernel<<<2048, 256, 0, stream>>>(z, nullptr, b3, c3, h3h, h3l, (t == 7) ? out : nullptr);
  }
}

// Round 5
// 1313.522 us; speedup vs baseline: 1.9500x; 1.2511x over previous
//
#include <hip/hip_runtime.h>
#include <hip/hip_bf16.h>

typedef unsigned short u16;
typedef __attribute__((ext_vector_type(8))) short short8;
typedef __attribute__((ext_vector_type(4))) float floatx4;

__device__ __forceinline__ u16 f2bf(float x) {
  unsigned u = __float_as_uint(x);
  u += 0x7fffu + ((u >> 16) & 1u);           // round-to-nearest-even to bf16
  return (u16)(u >> 16);
}
__device__ __forceinline__ float bf2f(u16 u) {
  return __uint_as_float(((unsigned)u) << 16);
}
__device__ __forceinline__ float sigm(float x) {
  return 1.0f / (1.0f + __expf(-x));
}

// ---------------- prep kernels ----------------

// x1,x2: (B=4, T=8, 128, 32, 32) fp32 -> X: [slot=t*4+b][1024 pix][256 ch] bf16 hi/lo
__global__ __launch_bounds__(256) void xsplit_kernel(
    const float* __restrict__ x1, const float* __restrict__ x2,
    u16* __restrict__ Xh, u16* __restrict__ Xl)
{
  __shared__ float lds[128][65];
  int bx  = blockIdx.x;              // 1024 blocks
  int sel = bx >> 9;                 // 0: x1, 1: x2
  int rem = bx & 511;
  int bt  = rem >> 4;                // b*8+t (source layout order)
  int pg  = rem & 15;                // 64-pixel group
  int b = bt >> 3, t = bt & 7;
  int p0 = pg << 6;
  const float* src = (sel ? x2 : x1) + ((size_t)bt << 17);
  int tid = threadIdx.x;
  #pragma unroll
  for (int k2 = 0; k2 < 8; ++k2) {
    int idx = tid + (k2 << 8);
    int c = idx >> 4, p4 = (idx & 15) << 2;
    floatx4 v = *reinterpret_cast<const floatx4*>(src + ((size_t)c << 10) + p0 + p4);
    lds[c][p4] = v[0]; lds[c][p4 + 1] = v[1]; lds[c][p4 + 2] = v[2]; lds[c][p4 + 3] = v[3];
  }
  __syncthreads();
  int pl = tid >> 2;                 // pixel 0..63
  int cg = (tid & 3) << 5;           // channel group
  size_t obase = (((size_t)((t * 4 + b) * 1024 + p0 + pl)) << 8) + (sel << 7) + cg;
  #pragma unroll
  for (int q = 0; q < 4; ++q) {
    short8 hv, lv;
    #pragma unroll
    for (int j = 0; j < 8; ++j) {
      float f = lds[cg + q * 8 + j][pl];
      u16 h = f2bf(f);
      hv[j] = (short)h;
      lv[j] = (short)f2bf(f - bf2f(h));
    }
    *reinterpret_cast<short8*>(Xh + obase + q * 8) = hv;
    *reinterpret_cast<short8*>(Xl + obase + q * 8) = lv;
  }
}

// W: (512, CIN, 3, 3) fp32 -> Wr rows REORDERED n' = oc*4 + gate:
// Wr[n'][k=(ky*3+kx)*CIN+ci] = W[(n'&3)*128 + (n'>>2)][ci][ky][kx], bf16 hi/lo
__global__ __launch_bounds__(256) void wsplit_kernel(
    const float* __restrict__ W, u16* __restrict__ Wh, u16* __restrict__ Wl, int CIN)
{
  int K = CIN * 9;
  int i = blockIdx.x * 256 + threadIdx.x;
  int np = i / K;
  int k = i - np * K;
  int e9 = k / CIN;
  int ci = k - e9 * CIN;
  int n = (np & 3) * 128 + (np >> 2);          // original row
  float v = W[((size_t)n * CIN + ci) * 9 + e9];
  u16 h = f2bf(v);
  Wh[i] = h;
  Wl[i] = f2bf(v - bf2f(h));
}

__global__ __launch_bounds__(256) void init_state(
    float* __restrict__ c1, float* __restrict__ c2, float* __restrict__ c3,
    u16* __restrict__ h1h, u16* __restrict__ h1l,
    u16* __restrict__ h2h, u16* __restrict__ h2l,
    u16* __restrict__ h3h, u16* __restrict__ h3l)
{
  int i = blockIdx.x * 256 + threadIdx.x;   // 524288
  c1[i] = 0.f; c2[i] = 0.f; c3[i] = 0.f;
  h1h[i] = 0; h1l[i] = 0; h2h[i] = 0; h2l[i] = 0; h3h[i] = 0; h3l[i] = 0;
}

// ---------------- conv as GEMM, BK=64, dbuf 1-barrier, optional fused gate ----
// z[m][n'] = sum_k A[m][k]*W[n'][k]; m=(slot,pix); k=(ky,kx,ci); n' = oc*4+g.
// Tile 64m x 64n', 256 thr (4 waves, wave-tile 32x32, 2x2 frags 16x16x32).
// LDS rows 128B (64 k bf16), XOR-swizzle (cq ^ (row&7)) * 16B. Double-buffered,
// ONE barrier per chunk. hi/lo split: acc += Ah*Wh + Ah*Wl + Al*Wh.
// FUSE=false: write z[m][512] (n'-ordered). FUSE=true: gate+state epilogue.
template<bool FUSE>
__global__ __launch_bounds__(256) void conv_gemm(
    const u16* __restrict__ A1h, const u16* __restrict__ A1l, int CA,
    const u16* __restrict__ A2h, const u16* __restrict__ A2l, int CB,
    const u16* __restrict__ Wh, const u16* __restrict__ Wl,
    int WCIN, int wcoff, int WK,
    float* __restrict__ zout,                  // FUSE=false
    const float* __restrict__ zx,              // FUSE=true (optional)
    const float* __restrict__ bias,            // FUSE=true
    float* __restrict__ c, u16* __restrict__ hh, u16* __restrict__ hl,
    float* __restrict__ hout)
{
  const int CIN = CA + CB;

  __shared__ __align__(16) char smem[65536];   // 2 bufs x (Ah|Al|Bh|Bl) x 8192B

  int tid = threadIdx.x;
  int bx  = blockIdx.x;
  int nt = bx & 7;          // 8 n-tiles
  int mt = bx >> 3;         // m-tiles
  int m0 = mt * 64;
  int slot = m0 >> 10;
  int pbase = m0 & 1023;
  int n0 = nt * 64;

  int lane = tid & 63;
  int wid  = tid >> 6;
  int wm = wid >> 1, wn = wid & 1;
  int fr = lane & 15, kq = lane >> 4;

  floatx4 acc[2][2];
  #pragma unroll
  for (int i2 = 0; i2 < 2; ++i2)
    #pragma unroll
    for (int j2 = 0; j2 < 2; ++j2)
      acc[i2][j2] = (floatx4)0.0f;

  // staging unit u = tid + 256*r: row = u>>3 (0..63), cq = u&7
  // chunk regs: RA[r] hi, RAl[r] lo, RB[r] hi, RBl[r] lo
  short8 RA[2], RAl[2], RB[2], RBl[2];

  const int ncc = CIN >> 6;       // 64-k chunks per e9 (CIN is 128 or 256)
  const int NQ = 9 * ncc;

  auto ldchunk = [&](int e9, int cc) {
    int dy = e9 / 3 - 1;
    int dx = e9 - (e9 / 3) * 3 - 1;
    // source select uniform per chunk (cc multiple of 64; CA multiple of 64)
    const u16 *sh, *sl; int cbase, CH;
    if (cc < CA) { sh = A1h; sl = A1l; cbase = cc;      CH = CA; }
    else         { sh = A2h; sl = A2l; cbase = cc - CA; CH = CB; }
    #pragma unroll
    for (int r = 0; r < 2; ++r) {
      int u = tid + 256 * r;
      int row = u >> 3, cq = u & 7;
      // A unit
      int yy = (pbase >> 5) + (row >> 5) + dy;
      int xx = (row & 31) + dx;
      bool valid = ((unsigned)yy < 32u) & ((unsigned)xx < 32u);
      short8 vh = (short8)0, vl = (short8)0;
      if (valid) {
        size_t ab = (size_t)(slot * 1024 + yy * 32 + xx) * CH + cbase + cq * 8;
        vh = *reinterpret_cast<const short8*>(sh + ab);
        vl = *reinterpret_cast<const short8*>(sl + ab);
      }
      RA[r] = vh; RAl[r] = vl;
      // B unit (same row/cq decomposition)
      size_t wb = (size_t)(n0 + row) * WK + wcoff + (size_t)e9 * WCIN + cc + cq * 8;
      RB[r]  = *reinterpret_cast<const short8*>(Wh + wb);
      RBl[r] = *reinterpret_cast<const short8*>(Wl + wb);
    }
  };

  auto stchunk = [&](int bs) {
    char* base = smem + bs * 32768;
    #pragma unroll
    for (int r = 0; r < 2; ++r) {
      int u = tid + 256 * r;
      int row = u >> 3, cq = u & 7;
      int off = row * 128 + (((cq ^ (row & 7)) & 7) << 4);   // XOR swizzle
      *reinterpret_cast<short8*>(base + off)          = RA[r];
      *reinterpret_cast<short8*>(base + 8192 + off)   = RAl[r];
      *reinterpret_cast<short8*>(base + 16384 + off)  = RB[r];
      *reinterpret_cast<short8*>(base + 24576 + off)  = RBl[r];
    }
  };

  auto compute = [&](int bs) {
    char* base = smem + bs * 32768;
    #pragma unroll
    for (int ks = 0; ks < 2; ++ks) {
      short8 vah[2], val[2], vbh[2], vbl[2];
      #pragma unroll
      for (int f = 0; f < 2; ++f) {
        int ar = wm * 32 + f * 16 + fr;
        int ao = ar * 128 + ((((ks * 4 + kq) ^ (ar & 7)) & 7) << 4);
        vah[f] = *reinterpret_cast<const short8*>(base + ao);
        val[f] = *reinterpret_cast<const short8*>(base + 8192 + ao);
        int br = wn * 32 + f * 16 + fr;
        int bo = br * 128 + ((((ks * 4 + kq) ^ (br & 7)) & 7) << 4);
        vbh[f] = *reinterpret_cast<const short8*>(base + 16384 + bo);
        vbl[f] = *reinterpret_cast<const short8*>(base + 24576 + bo);
      }
      __builtin_amdgcn_s_setprio(1);
      #pragma unroll
      for (int mf = 0; mf < 2; ++mf)
        #pragma unroll
        for (int nf = 0; nf < 2; ++nf) {
          acc[mf][nf] = __builtin_amdgcn_mfma_f32_16x16x32_bf16(vah[mf], vbh[nf], acc[mf][nf], 0, 0, 0);
          acc[mf][nf] = __builtin_amdgcn_mfma_f32_16x16x32_bf16(vah[mf], vbl[nf], acc[mf][nf], 0, 0, 0);
          acc[mf][nf] = __builtin_amdgcn_mfma_f32_16x16x32_bf16(val[mf], vbh[nf], acc[mf][nf], 0, 0, 0);
        }
      __builtin_amdgcn_s_setprio(0);
    }
  };

  // ---- main loop: 1 barrier per 64-k chunk ----
  ldchunk(0, 0);
  stchunk(0);                 // buf0 pre-filled (visible after first barrier)
  int e9 = 0, cc = 0;
  for (int q = 0; q < NQ; ++q) {
    int ccn = cc + 64, e9n = e9;
    if (ccn == CIN) { ccn = 0; e9n++; }
    bool more = (q + 1 < NQ);
    if (more) ldchunk(e9n, ccn);
    __syncthreads();          // buf[q&1] writes visible; buf[(q+1)&1] reads done
    if (more) stchunk((q + 1) & 1);
    compute(q & 1);
    e9 = e9n; cc = ccn;
  }

  if (!FUSE) {
    // direct z[m][n'] stores (16-lane / 64B coalesced groups)
    #pragma unroll
    for (int mf = 0; mf < 2; ++mf)
      #pragma unroll
      for (int nf = 0; nf < 2; ++nf) {
        int n = n0 + wn * 32 + nf * 16 + fr;
        int mb = m0 + wm * 32 + mf * 16 + kq * 4;
        #pragma unroll
        for (int r = 0; r < 4; ++r)
          zout[((size_t)(mb + r) << 9) + n] = acc[mf][nf][r];
      }
    return;
  }

  // ---- fused gate epilogue ----
  __syncthreads();            // all frag reads done before smem reuse
  float (*tr)[33] = reinterpret_cast<float(*)[33]>(smem + wid * 4352);  // 32x33 f32/wave
  #pragma unroll
  for (int mf = 0; mf < 2; ++mf)
    #pragma unroll
    for (int nf = 0; nf < 2; ++nf)
      #pragma unroll
      for (int r = 0; r < 4; ++r)
        tr[mf * 16 + kq * 4 + r][nf * 16 + fr] = acc[mf][nf][r];
  // intra-wave read-back (compiler inserts lgkmcnt waits)
  int ocl = lane & 7;
  int ocg = nt * 16 + wn * 8 + ocl;
  #pragma unroll
  for (int it = 0; it < 4; ++it) {
    int m = (lane >> 3) * 4 + it;          // 0..31
    int ppix = pbase + wm * 32 + m;
    size_t grow = (size_t)slot * 1024 + ppix;
    float zg[4];
    if (zx) {
      floatx4 zv = *reinterpret_cast<const floatx4*>(zx + (grow << 9) + ocg * 4);
      #pragma unroll
      for (int g = 0; g < 4; ++g) zg[g] = tr[m][ocl * 4 + g] + zv[g] + bias[g * 128 + ocg];
    } else {
      #pragma unroll
      for (int g = 0; g < 4; ++g) zg[g] = tr[m][ocl * 4 + g] + bias[g * 128 + ocg];
    }
    size_t cidx = grow * 128 + ocg;
    float cv = c[cidx];
    float cn = sigm(zg[1]) * cv + sigm(zg[0]) * tanhf(zg[3]);
    float hn = sigm(zg[2]) * tanhf(cn);
    c[cidx] = cn;
    u16 hb = f2bf(hn);
    hh[cidx] = hb;
    hl[cidx] = f2bf(hn - bf2f(hb));
    if (hout) hout[((size_t)slot * 128 + ocg) * 1024 + ppix] = hn;   // NCHW
  }
}

extern "C" void kernel_launch(void* const* d_in, const int* in_sizes, int n_in,
                              void* d_out, int out_size, void* d_ws, size_t ws_size,
                              hipStream_t stream)
{
  const float* x1 = (const float*)d_in[0];
  const float* x2 = (const float*)d_in[1];
  const float* W1 = (const float*)d_in[2];
  const float* b1 = (const float*)d_in[3];
  const float* W2 = (const float*)d_in[4];
  const float* b2 = (const float*)d_in[5];
  const float* W3 = (const float*)d_in[6];
  const float* b3 = (const float*)d_in[7];
  float* out = (float*)d_out;

  char* ws = (char*)d_ws;
  size_t off = 0;
  auto alloc = [&](size_t bytes) {
    char* p = ws + off;
    off += (bytes + 255) & ~(size_t)255;
    return p;
  };
  u16*   Xh  = (u16*)  alloc(16777216);   // [32 slot][1024][256]
  u16*   Xl  = (u16*)  alloc(16777216);
  u16*   W1h = (u16*)  alloc(3538944);    // [512][3456] (rows n'-reordered)
  u16*   W1l = (u16*)  alloc(3538944);
  u16*   W2h = (u16*)  alloc(2359296);    // [512][2304]
  u16*   W2l = (u16*)  alloc(2359296);
  u16*   W3h = (u16*)  alloc(2359296);
  u16*   W3l = (u16*)  alloc(2359296);
  u16*   hb_[12];                         // h ping-pong: layer x {h,l} x parity
  for (int i = 0; i < 12; ++i) hb_[i] = (u16*)alloc(1048576);   // [4][1024][128]
  float* c1  = (float*)alloc(2097152);    // [4][1024][128] fp32
  float* c2  = (float*)alloc(2097152);
  float* c3  = (float*)alloc(2097152);
  float* zx  = (float*)alloc(67108864);   // [32 slot][1024][512] fp32
  if (off > ws_size) return;

  u16 **h1h = &hb_[0], **h1l = &hb_[2], **h2h = &hb_[4], **h2l = &hb_[6],
      **h3h = &hb_[8], **h3l = &hb_[10];
  // (pointer arrays on host stack; values baked into kernel args per launch)

  xsplit_kernel<<<1024, 256, 0, stream>>>(x1, x2, Xh, Xl);
  wsplit_kernel<<<6912, 256, 0, stream>>>(W1, W1h, W1l, 384);
  wsplit_kernel<<<4608, 256, 0, stream>>>(W2, W2h, W2l, 256);
  wsplit_kernel<<<4608, 256, 0, stream>>>(W3, W3h, W3l, 256);
  init_state<<<2048, 256, 0, stream>>>(c1, c2, c3,
      hb_[0], hb_[2], hb_[4], hb_[6], hb_[8], hb_[10]);   // parity-0 buffers

  // big GEMM: L1 x-contribution for all T (M=32768, K=2304) -> zx[m][n']
  conv_gemm<false><<<4096, 256, 0, stream>>>(
      Xh, Xl, 256, nullptr, nullptr, 0, W1h, W1l, 384, 0, 3456,
      zx, nullptr, nullptr, nullptr, nullptr, nullptr, nullptr);

  for (int t = 0; t < 8; ++t) {
    int pi = t & 1, po = pi ^ 1;
    const float* zxt = zx + (size_t)t * 2097152;
    // layer 1: h-part (K=1152, W1 channels 256..383) + zx + gates -> h1,c1
    conv_gemm<true><<<512, 256, 0, stream>>>(
        h1h[pi], h1l[pi], 128, nullptr, nullptr, 0, W1h, W1l, 384, 256, 3456,
        nullptr, zxt, b1, c1, h1h[po], h1l[po], nullptr);
    // layer 2: [h1_new, h2_old]
    conv_gemm<true><<<512, 256, 0, stream>>>(
        h1h[po], h1l[po], 128, h2h[pi], h2l[pi], 128, W2h, W2l, 256, 0, 2304,
        nullptr, nullptr, b2, c2, h2h[po], h2l[po], nullptr);
    // layer 3: [h2_new, h3_old]
    conv_gemm<true><<<512, 256, 0, stream>>>(
        h2h[po], h2l[po], 128, h3h[pi], h3l[pi], 128, W3h, W3l, 256, 0, 2304,
        nullptr, nullptr, b3, c3, h3h[po], h3l[po], (t == 7) ? out : nullptr);
  }
}